// Round 6
// baseline (173.140 us; speedup 1.0000x reference)
//
#include <hip/hip_runtime.h>

#define ED 1024      // EMBED_DIM
#define AD 256       // ATTN_DIM
#define BB 16        // batch
#define NK 4096      // keys
#define NCH 64       // v-chunks per batch
#define KCH (NK/NCH) // 64 rows per chunk

// ws layout (floats):
#define OFF_QP    0          // BB*AD       = 4096
#define OFF_T     4096       // BB*ED       = 16384
#define OFF_WSUM  20480      // BB*NCH      = 1024
#define OFF_PART  21504      // BB*NCH*ED   = 1048576
#define OFF_OV    1070080    // BB*ED       = 16384
#define OFF_OPART 1086464    // 4*BB*ED     = 65536

// ---------------------------------------------------------------------------
// Kernel 1: qp[b,c] = bkq[c] + sum_d q[b,d]*Wkq[d,c].  grid (16,4), block 256.
__global__ void k_qp(const float* __restrict__ q, const float* __restrict__ Wkq,
                     const float* __restrict__ bkq, float* __restrict__ qp) {
    int b = blockIdx.x, cg = blockIdx.y, tid = threadIdx.x;
    int c = cg * 64 + (tid & 63), dg = tid >> 6;
    __shared__ float qsh[ED];
    ((float4*)qsh)[tid] = ((const float4*)(q + b * ED))[tid];
    __syncthreads();
    float acc = 0.f;
    #pragma unroll 8
    for (int d = dg; d < ED; d += 4) acc += qsh[d] * Wkq[(size_t)d * AD + c];
    __shared__ float red[4][64];
    red[dg][tid & 63] = acc;
    __syncthreads();
    if (tid < 64) {
        float s = red[0][tid] + red[1][tid] + red[2][tid] + red[3][tid];
        qp[b * AD + cg * 64 + tid] = s + bkq[cg * 64 + tid];
    }
}

// Kernel 2: t[b,d] = Wkq[d,:].qp[b,:]. grid (8,16), block 256, 2-row ILP.
__global__ void k_t(const float* __restrict__ Wkq, const float* __restrict__ qp,
                    float* __restrict__ t) {
    int b = blockIdx.y, dbase = blockIdx.x * 128;
    int tid = threadIdx.x, wave = tid >> 6, lane = tid & 63;
    float4 qv = ((const float4*)(qp + b * AD))[lane];
    for (int r = 0; r < 16; ++r) {
        int d1 = dbase + wave * 32 + r;
        int d2 = d1 + 16;
        float4 w1 = ((const float4*)(Wkq + (size_t)d1 * AD))[lane];
        float4 w2 = ((const float4*)(Wkq + (size_t)d2 * AD))[lane];
        float s1 = w1.x*qv.x + w1.y*qv.y + w1.z*qv.z + w1.w*qv.w;
        float s2 = w2.x*qv.x + w2.y*qv.y + w2.z*qv.z + w2.w*qv.w;
        #pragma unroll
        for (int off = 32; off; off >>= 1) {
            s1 += __shfl_down(s1, off, 64);
            s2 += __shfl_down(s2, off, 64);
        }
        if (lane == 0) { t[b * ED + d1] = s1; t[b * ED + d2] = s2; }
    }
}

// Kernel 3 (fused, software-pipelined): wave handles 16 rows; prefetch row
// r+1's k AND v into named registers before consuming row r. launch_bounds
// raises the VGPR cap (round-5 profile showed a 32-VGPR allocation that
// serialized all loads -> 3.5 TB/s). grid (NCH, BB), block 256.
__global__ __launch_bounds__(256, 2)
void k_fused(const float* __restrict__ k, const float* __restrict__ v,
             const float* __restrict__ t, float* __restrict__ partial,
             float* __restrict__ wsum) {
    int ch = blockIdx.x, b = blockIdx.y;
    int tid = threadIdx.x, wave = tid >> 6, lane = tid & 63;
    const float4* tb = (const float4*)(t + b * ED);
    float4 t0 = tb[lane], t1 = tb[64 + lane], t2 = tb[128 + lane], t3 = tb[192 + lane];
    int row0 = ch * KCH + wave * 16;
    const float4* kbase = (const float4*)(k + ((size_t)b * NK + row0) * ED);
    const float4* vbase = (const float4*)(v + ((size_t)b * NK + row0) * ED);
    float4 acc0 = {0,0,0,0}, acc1 = {0,0,0,0}, acc2 = {0,0,0,0}, acc3 = {0,0,0,0};
    float wacc = 0.f;
    // prologue: row 0 in flight
    float4 ka0 = kbase[lane], ka1 = kbase[64 + lane], ka2 = kbase[128 + lane], ka3 = kbase[192 + lane];
    float4 va0 = vbase[lane], va1 = vbase[64 + lane], va2 = vbase[128 + lane], va3 = vbase[192 + lane];
    #pragma unroll
    for (int r = 0; r < 16; ++r) {
        int rn = (r < 15) ? r + 1 : 15;          // clamp: avoid OOB on last row
        const float4* krn = kbase + (size_t)rn * (ED / 4);
        const float4* vrn = vbase + (size_t)rn * (ED / 4);
        // issue next row's 8 loads before touching current row
        float4 kb0 = krn[lane], kb1 = krn[64 + lane], kb2 = krn[128 + lane], kb3 = krn[192 + lane];
        float4 vb0 = vrn[lane], vb1 = vrn[64 + lane], vb2 = vrn[128 + lane], vb3 = vrn[192 + lane];
        float s = ka0.x*t0.x + ka0.y*t0.y + ka0.z*t0.z + ka0.w*t0.w
                + ka1.x*t1.x + ka1.y*t1.y + ka1.z*t1.z + ka1.w*t1.w
                + ka2.x*t2.x + ka2.y*t2.y + ka2.z*t2.z + ka2.w*t2.w
                + ka3.x*t3.x + ka3.y*t3.y + ka3.z*t3.z + ka3.w*t3.w;
        #pragma unroll
        for (int m = 32; m; m >>= 1) s += __shfl_xor(s, m, 64);
        float w = __expf(s * 0.0625f);
        wacc += w;
        acc0.x += w*va0.x; acc0.y += w*va0.y; acc0.z += w*va0.z; acc0.w += w*va0.w;
        acc1.x += w*va1.x; acc1.y += w*va1.y; acc1.z += w*va1.z; acc1.w += w*va1.w;
        acc2.x += w*va2.x; acc2.y += w*va2.y; acc2.z += w*va2.z; acc2.w += w*va2.w;
        acc3.x += w*va3.x; acc3.y += w*va3.y; acc3.z += w*va3.z; acc3.w += w*va3.w;
        ka0 = kb0; ka1 = kb1; ka2 = kb2; ka3 = kb3;
        va0 = vb0; va1 = vb1; va2 = vb2; va3 = vb3;
    }
    __shared__ float4 red[4][256];   // 16 KB: [wave][float4-slot]
    red[wave][lane]       = acc0;
    red[wave][64 + lane]  = acc1;
    red[wave][128 + lane] = acc2;
    red[wave][192 + lane] = acc3;
    __shared__ float wred[4];
    if (lane == 0) wred[wave] = wacc;   // wacc uniform across lanes
    __syncthreads();
    float4 a0 = red[0][tid], a1 = red[1][tid], a2 = red[2][tid], a3 = red[3][tid];
    float4 r4;
    r4.x = a0.x + a1.x + a2.x + a3.x;
    r4.y = a0.y + a1.y + a2.y + a3.y;
    r4.z = a0.z + a1.z + a2.z + a3.z;
    r4.w = a0.w + a1.w + a2.w + a3.w;
    ((float4*)partial)[((size_t)(b * NCH + ch)) * (ED / 4) + tid] = r4;
    if (tid == 0) wsum[b * NCH + ch] = wred[0] + wred[1] + wred[2] + wred[3];
}

// Kernel 4: ov[b, dq*256..] = (sum_ch partial[b,ch,dq*256..]) / l[b].
// grid (16,4), block 256 = 4 ch-groups x 64 float4-cols.
__global__ void k_reduce(const float* __restrict__ partial, const float* __restrict__ wsum,
                         float* __restrict__ ov) {
    int b = blockIdx.x, dq = blockIdx.y, tid = threadIdx.x;
    int chg = tid >> 6, c = tid & 63;
    __shared__ float lsh;
    if (tid < 64) {
        float s = wsum[b * NCH + tid];
        #pragma unroll
        for (int off = 32; off; off >>= 1) s += __shfl_down(s, off, 64);
        if (tid == 0) lsh = s;
    }
    const float4* pb = (const float4*)(partial + (size_t)b * NCH * ED);
    float4 s4 = {0.f, 0.f, 0.f, 0.f};
    #pragma unroll 8
    for (int ch = chg; ch < NCH; ch += 4) {
        float4 p = pb[(size_t)ch * (ED / 4) + dq * 64 + c];
        s4.x += p.x; s4.y += p.y; s4.z += p.z; s4.w += p.w;
    }
    __shared__ float4 red[4][64];
    red[chg][c] = s4;
    __syncthreads();
    if (tid < 64) {
        float4 a0 = red[0][tid], a1 = red[1][tid], a2 = red[2][tid], a3 = red[3][tid];
        float linv = 1.0f / lsh;
        float4 r;
        r.x = (a0.x + a1.x + a2.x + a3.x) * linv;
        r.y = (a0.y + a1.y + a2.y + a3.y) * linv;
        r.z = (a0.z + a1.z + a2.z + a3.z) * linv;
        r.w = (a0.w + a1.w + a2.w + a3.w) * linv;
        ((float4*)(ov + b * ED + dq * 256))[tid] = r;
    }
}

// Kernel 5: out_part[dq][b][col] = sum_{d in quarter} ov[b,d]*Wv[d,col].
// grid (16 colblocks, 4 d-quarters), block 256 = 4 d-groups x 64 cols.
__global__ void k_out(const float* __restrict__ ov, const float* __restrict__ Wv,
                      float* __restrict__ opart) {
    int cb = blockIdx.x, dq = blockIdx.y, tid = threadIdx.x;
    int col = cb * 64 + (tid & 63), dg = tid >> 6;
    __shared__ float ovsh[BB][256];
    for (int i = tid; i < BB * 64; i += 256) {
        int bb = i >> 6, c4 = i & 63;
        ((float4*)ovsh[bb])[c4] = ((const float4*)(ov + bb * ED + dq * 256))[c4];
    }
    __syncthreads();
    float acc[BB];
    #pragma unroll
    for (int b = 0; b < BB; ++b) acc[b] = 0.f;
    #pragma unroll 8
    for (int it = 0; it < 64; ++it) {
        int dd = dg + it * 4;
        float w = Wv[(size_t)(dq * 256 + dd) * ED + col];
        #pragma unroll
        for (int b = 0; b < BB; ++b) acc[b] += ovsh[b][dd] * w;
    }
    __shared__ float red[BB][256];
    #pragma unroll
    for (int b = 0; b < BB; ++b) red[b][tid] = acc[b];
    __syncthreads();
    int bgrp = tid >> 6, c = tid & 63;
    #pragma unroll
    for (int bi = 0; bi < 4; ++bi) {
        int b = bgrp * 4 + bi;
        float s = red[b][c] + red[b][64 + c] + red[b][128 + c] + red[b][192 + c];
        opart[((size_t)(dq * BB + b)) * ED + cb * 64 + c] = s;
    }
}

// Kernel 6: out[b,:] = sum_dq out_part[dq][b][:] + bv. grid 16, block 256.
__global__ void k_final(const float* __restrict__ opart, const float* __restrict__ bv,
                        float* __restrict__ out) {
    int b = blockIdx.x, tid = threadIdx.x;
    float4 s = ((const float4*)(opart + (size_t)(0 * BB + b) * ED))[tid];
    #pragma unroll
    for (int dq = 1; dq < 4; ++dq) {
        float4 p = ((const float4*)(opart + (size_t)(dq * BB + b) * ED))[tid];
        s.x += p.x; s.y += p.y; s.z += p.z; s.w += p.w;
    }
    float4 bb = ((const float4*)bv)[tid];
    s.x += bb.x; s.y += bb.y; s.z += bb.z; s.w += bb.w;
    ((float4*)(out + b * ED))[tid] = s;
}

extern "C" void kernel_launch(void* const* d_in, const int* in_sizes, int n_in,
                              void* d_out, int out_size, void* d_ws, size_t ws_size,
                              hipStream_t stream) {
    const float* q   = (const float*)d_in[0];
    const float* k   = (const float*)d_in[1];
    const float* v   = (const float*)d_in[2];
    const float* Wkq = (const float*)d_in[3];
    const float* bkq = (const float*)d_in[4];
    const float* Wv  = (const float*)d_in[5];
    const float* bv  = (const float*)d_in[6];
    float* out = (float*)d_out;
    float* ws  = (float*)d_ws;

    float* qp      = ws + OFF_QP;
    float* t       = ws + OFF_T;
    float* wsum    = ws + OFF_WSUM;
    float* partial = ws + OFF_PART;
    float* ov      = ws + OFF_OV;
    float* opart   = ws + OFF_OPART;

    k_qp    <<<dim3(16, 4),   256, 0, stream>>>(q, Wkq, bkq, qp);
    k_t     <<<dim3(8, 16),   256, 0, stream>>>(Wkq, qp, t);
    k_fused <<<dim3(NCH, BB), 256, 0, stream>>>(k, v, t, partial, wsum);
    k_reduce<<<dim3(16, 4),   256, 0, stream>>>(partial, wsum, ov);
    k_out   <<<dim3(16, 4),   256, 0, stream>>>(ov, Wv, opart);
    k_final <<<16,            256, 0, stream>>>(opart, bv, out);
}